// Round 11
// baseline (49.738 us; speedup 1.0000x reference)
//
#include <hip/hip_runtime.h>
#include <hip/hip_bf16.h>

// ST-GCN spatial graph conv — swapped contraction, single-wave, zero-LDS,
// zero-barrier, in-register two-stage MFMA. R11: ALL loads issued up front,
// pinned by sched_barrier(0) so the compiler cannot sink/serialize them.
//
//   stage A (per n,t):  y[ci][32k+w] = sum_v x[n,ci,t,v] * A[k,v,w]
//       K-axis = v -> per-lane x frag = 8 consecutive floats (2 aligned f32x4),
//       d = t&3 dword phase handled by 4 pre-shifted Ahat images.
//   stage B:  out[c][w] = sum_{k,ci} W[64k+c][ci] * y[ci][32k+w]
//       W2img pre-permuted so each lane's B-frag == its own stage-A acc values.
//   bias folded into boutT init image.
//
// 9600 waves (one per (n,t)), 2400 blocks x 256 thr. 72 MFMA, 46 vec loads/wave
// — all concurrently in flight.

#define CIN   64
#define T_    300
#define V_    25
#define COUT  64

#define WS_W2 0        // 24576 B : bf16 W2img[(ct*6+kap)*64 + lane][8]
#define WS_AH 24576    // 24576 B : bf16 AhatT4[d(4)][kw(96)][vp(32)]
#define WS_BO 49152    // 8192  B : f32  boutT[w(32)][c(64)]
#define WS_BYTES 57344

typedef short  bf16x8 __attribute__((ext_vector_type(8)));
typedef float  f32x4  __attribute__((ext_vector_type(4)));

__device__ __forceinline__ unsigned short cvt_bf16(float f) {
    union { __hip_bfloat16 h; unsigned short u; } cv;
    cv.h = __float2bfloat16(f);
    return cv.u;
}
__device__ __forceinline__ unsigned pk2(float a, float b) {
    return (unsigned)cvt_bf16(a) | ((unsigned)cvt_bf16(b) << 16);
}
union fragu { bf16x8 v; unsigned u[4]; };

// ---------------- prepass: bake W2img / AhatT4 / boutT ----------------
__global__ void gcn_prep(const float* __restrict__ W, const float* __restrict__ bias,
                         const float* __restrict__ A, unsigned char* __restrict__ ws)
{
    const int tid = blockIdx.x * 256 + threadIdx.x;   // 4096 threads
    // W2img[((ct*6+kap)*64 + lane)*8 + e] = W[(kap>>1)*64+16ct+lr][32(kap&1)+16(e>>2)+4lq+(e&3)]
    for (int i = tid; i < 4 * 6 * 64 * 8; i += 4096) {
        const int e = i & 7, lane = (i >> 3) & 63, ck = i >> 9;
        const int kap = ck % 6, ct = ck / 6;
        const int lr = lane & 15, lq = lane >> 4;
        const int row = (kap >> 1) * COUT + ct * 16 + lr;
        const int col = 32 * (kap & 1) + 16 * (e >> 2) + 4 * lq + (e & 3);
        reinterpret_cast<unsigned short*>(ws + WS_W2)[i] = cvt_bf16(W[row * CIN + col]);
    }
    // AhatT4[d][kw][vp] = A[kw>>5][vp-d][kw&31]  (0 outside v in [0,25), w<25)
    for (int i = tid; i < 4 * 96 * 32; i += 4096) {
        const int vp = i & 31, kw = (i >> 5) % 96, dd = (i >> 5) / 96;
        const int k = kw >> 5, w = kw & 31, v = vp - dd;
        const float val = (v >= 0 && v < V_ && w < V_) ? A[(k * V_ + v) * V_ + w] : 0.f;
        reinterpret_cast<unsigned short*>(ws + WS_AH)[i] = cvt_bf16(val);
    }
    // boutT[w][c] = sum_k b[64k+c] * sum_v A[k,v,w]
    for (int i = tid; i < 32 * 64; i += 4096) {
        const int w = i >> 6, c = i & 63;
        float s = 0.f;
        if (w < V_) {
            for (int k = 0; k < 3; ++k) {
                float sa = 0.f;
                for (int v = 0; v < V_; ++v) sa += A[(k * V_ + v) * V_ + w];
                s += bias[k * COUT + c] * sa;
            }
        }
        reinterpret_cast<float*>(ws + WS_BO)[i] = s;
    }
}

// ---------------- main: 1 wave = 1 (n,t) ----------------
__global__ __launch_bounds__(256, 2) void gcn_main(
    const float* __restrict__ x, const unsigned char* __restrict__ ws,
    float* __restrict__ out)
{
    const int tid = threadIdx.x;
    const int l = tid & 63, lr = l & 15, lq = l >> 4;
    const int gid = blockIdx.x * 4 + (tid >> 6);      // 0..9599
    const int n = gid / T_, t = gid % T_;
    const int d = t & 3;                              // wave-uniform dword phase
    const int qoff = t * V_ - d;                      // 16B-aligned float offset

    // ================= LOAD BLOCK: all 46 vector loads issued here =================
    // x: 8 aligned f32x4
    const float* xrow = x + (size_t)(n * CIN + lr) * (T_ * V_) + qoff + 8 * lq;
    f32x4 xa[4], xg[4];
    #pragma unroll
    for (int mi = 0; mi < 4; ++mi) {
        const float* p = xrow + (size_t)mi * 16 * (T_ * V_);
        xa[mi] = *reinterpret_cast<const f32x4*>(p);
        // lq==3: vp=28..31 hits all-zero Ahat rows -> load dup of first chunk
        xg[mi] = *reinterpret_cast<const f32x4*>(p + (lq < 3 ? 4 : 0));
    }
    // Ahat frags (6)
    const unsigned char* ahb = ws + WS_AH + d * (96 * 32 * 2);
    bf16x8 ah[6];
    #pragma unroll
    for (int ni = 0; ni < 6; ++ni)
        ah[ni] = *reinterpret_cast<const bf16x8*>(ahb + ((16 * ni + lr) * 32 + 8 * lq) * 2);
    // bout init (8)
    f32x4 oacc[4][2];
    #pragma unroll
    for (int ct = 0; ct < 4; ++ct)
        #pragma unroll
        for (int nt = 0; nt < 2; ++nt)
            oacc[ct][nt] = *reinterpret_cast<const f32x4*>(
                ws + WS_BO + ((16 * nt + lr) * 64 + 16 * ct + 4 * lq) * 4);
    // W2 frags, ALL k (24)
    bf16x8 w2fa[6][4];
    #pragma unroll
    for (int kap = 0; kap < 6; ++kap)
        #pragma unroll
        for (int ct = 0; ct < 4; ++ct)
            w2fa[kap][ct] = *reinterpret_cast<const bf16x8*>(
                ws + WS_W2 + ((ct * 6 + kap) * 64 + l) * 16);

    // compile-time fence: no load may sink below, no use may hoist above
    __builtin_amdgcn_sched_barrier(0);
    // ===============================================================================

    // ---- x -> bf16 A-frags
    bf16x8 xf[4];
    #pragma unroll
    for (int mi = 0; mi < 4; ++mi) {
        fragu f;
        f.u[0] = pk2(xa[mi][0], xa[mi][1]);
        f.u[1] = pk2(xa[mi][2], xa[mi][3]);
        f.u[2] = pk2(xg[mi][0], xg[mi][1]);
        f.u[3] = pk2(xg[mi][2], xg[mi][3]);
        xf[mi] = f.v;
    }

    // ---- fused stages, per k: stage A (8 MFMA) -> handoff -> stage B (16 MFMA)
    #pragma unroll
    for (int k = 0; k < 3; ++k) {
        f32x4 y[4][2];
        #pragma unroll
        for (int mi = 0; mi < 4; ++mi)
            #pragma unroll
            for (int j = 0; j < 2; ++j)
                y[mi][j] = (f32x4){0.f, 0.f, 0.f, 0.f};
        #pragma unroll
        for (int j = 0; j < 2; ++j)
            #pragma unroll
            for (int mi = 0; mi < 4; ++mi)
                y[mi][j] = __builtin_amdgcn_mfma_f32_16x16x32_bf16(
                    xf[mi], ah[2 * k + j], y[mi][j], 0, 0, 0);

        // handoff: B-frag[e] = bf16(y[2kl + (e>>2)][nt][e&3]) — all lane-local
        #pragma unroll
        for (int kl = 0; kl < 2; ++kl)
            #pragma unroll
            for (int nt = 0; nt < 2; ++nt) {
                fragu b;
                b.u[0] = pk2(y[2 * kl][nt][0],     y[2 * kl][nt][1]);
                b.u[1] = pk2(y[2 * kl][nt][2],     y[2 * kl][nt][3]);
                b.u[2] = pk2(y[2 * kl + 1][nt][0], y[2 * kl + 1][nt][1]);
                b.u[3] = pk2(y[2 * kl + 1][nt][2], y[2 * kl + 1][nt][3]);
                #pragma unroll
                for (int ct = 0; ct < 4; ++ct)
                    oacc[ct][nt] = __builtin_amdgcn_mfma_f32_16x16x32_bf16(
                        w2fa[2 * k + kl][ct], b.v, oacc[ct][nt], 0, 0, 0);
            }
    }

    // ---- store: lane holds out[c = 16ct+4lq+r][w = 16nt+lr]
    float* ob = out + ((size_t)(n * COUT) * T_ + t) * V_;
    #pragma unroll
    for (int ct = 0; ct < 4; ++ct) {
        #pragma unroll
        for (int r = 0; r < 4; ++r) {
            const int c = 16 * ct + 4 * lq + r;
            float* op = ob + (size_t)c * (T_ * V_);
            op[lr] = oacc[ct][0][r];
            if (lr < 9) op[16 + lr] = oacc[ct][1][r];
        }
    }
}

extern "C" void kernel_launch(void* const* d_in, const int* in_sizes, int n_in,
                              void* d_out, int out_size, void* d_ws, size_t ws_size,
                              hipStream_t stream) {
    const float* x    = (const float*)d_in[0];
    const float* W    = (const float*)d_in[1];
    const float* bias = (const float*)d_in[2];
    const float* A    = (const float*)d_in[3];
    float* out = (float*)d_out;
    unsigned char* ws = (unsigned char*)d_ws;   // needs WS_BYTES = 57344

    hipLaunchKernelGGL(gcn_prep, dim3(16), dim3(256), 0, stream, W, bias, A, ws);
    hipLaunchKernelGGL(gcn_main, dim3(2400), dim3(256), 0, stream, x, ws, out);
}